// Round 9
// baseline (693.373 us; speedup 1.0000x reference)
//
#include <hip/hip_runtime.h>

#define NLAYER 12
#define NB 16
#define NH 12
#define NN 197
#define MAT (NN * NN)   // 38809
#define KSEL 98         // int(197 * 0.5)

// Initialize output to "not selected" = [1, 0] for every (b, n).
__global__ void init_out_kernel(float* __restrict__ out)
{
    int i = blockIdx.x * blockDim.x + threadIdx.x;  // [0, NB*NN)
    if (i < NB * NN) {
        out[2 * i + 0] = 1.f;
        out[2 * i + 1] = 0.f;
    }
}

// One block (256 threads) per (tensor, b, h): compute
// v = e0^T * A11 * A10 * ... * A0 via ping-pong vector in LDS,
// one barrier per layer. Then top-KSEL of v[1..196] by rank count,
// writing [0,1] at selected (b, j). Concurrent writers store identical
// values (benign race).
__global__ __launch_bounds__(256) void chain_topk_kernel(
    const float* __restrict__ RGB, const float* __restrict__ TIR,
    float* __restrict__ out)
{
    __shared__ float vbuf[2][NN];

    int bid = blockIdx.x;                 // [0, 2*NB*NH)
    int tensor = bid / (NB * NH);
    int rem = bid - tensor * (NB * NH);
    int b = rem / NH;
    int h = rem - b * NH;

    const float* A = tensor ? TIR : RGB;
    const size_t bh_off = (size_t)(b * NH + h) * MAT;      // layer-l base += l*l_stride
    const size_t l_stride = (size_t)NB * NH * MAT;

    int j = threadIdx.x;   // output column this thread owns (j < NN active)

    // init: v = row 0 of layer 11 (coalesced)
    if (j < NN) vbuf[0][j] = A[bh_off + 11 * l_stride + j];
    __syncthreads();

    int cur = 0;
    for (int l = 10; l >= 0; --l) {
        const float* M = A + bh_off + (size_t)l * l_stride;
        if (j < NN) {
            const float* col = M + j;          // column j, stride NN
            const float* v = vbuf[cur];
            float acc = 0.f;
            #pragma unroll 16
            for (int k = 0; k < NN; ++k)       // lanes j..j+63 coalesced per k
                acc = fmaf(v[k], col[(size_t)k * NN], acc);
            vbuf[cur ^ 1][j] = acc;            // other buffer: no WAR hazard
        }
        __syncthreads();                       // single barrier per layer
        cur ^= 1;
    }

    // top-KSEL of scores = vbuf[cur][1..196] via rank counting.
    // Strict '>' reproduces top_k's set for distinct values; a borderline
    // fp-ordering flip only matters if NONE of the other 23 (tensor,h)
    // selections pick that element (P ~ 2^-23).
    const float* vf = vbuf[cur];
    if (j < NN - 1) {
        float my = vf[1 + j];
        int rank = 0;
        for (int k = 0; k < NN - 1; ++k)
            rank += (vf[1 + k] > my) ? 1 : 0;
        if (rank < KSEL) {
            out[2 * (b * NN + j) + 0] = 0.f;
            out[2 * (b * NN + j) + 1] = 1.f;
        }
    }
}

extern "C" void kernel_launch(void* const* d_in, const int* in_sizes, int n_in,
                              void* d_out, int out_size, void* d_ws, size_t ws_size,
                              hipStream_t stream) {
    const float* RGB = (const float*)d_in[0];
    const float* TIR = (const float*)d_in[1];
    float* out = (float*)d_out;

    int total = NB * NN;
    init_out_kernel<<<(total + 255) / 256, 256, 0, stream>>>(out);

    chain_topk_kernel<<<2 * NB * NH, 256, 0, stream>>>(RGB, TIR, out);
}

// Round 11
// 650.031 us; speedup vs baseline: 1.0667x; 1.0667x over previous
//
#include <hip/hip_runtime.h>

#define NB 16
#define NH 12
#define NN 197
#define MAT (NN * NN)   // 38809
#define KSEL 98         // int(197 * 0.5)

// Initialize output to "not selected" = [1, 0] for every (b, n).
__global__ void init_out_kernel(float* __restrict__ out)
{
    int i = blockIdx.x * blockDim.x + threadIdx.x;  // [0, NB*NN)
    if (i < NB * NN) {
        out[2 * i + 0] = 1.f;
        out[2 * i + 1] = 0.f;
    }
}

// One block (1024 threads = 16 waves) per (tensor, b, h):
// v = e0^T * A11 * ... * A0 with ping-pong v in LDS.
// Thread (j = tid&255) owns column j; q = tid>>8 owns a k-quarter.
// Inner loop issues 16 independent global loads into registers before
// consuming them (deep pipeline -> many outstanding loads per wave).
__global__ __launch_bounds__(1024) void chain_topk_kernel(
    const float* __restrict__ RGB, const float* __restrict__ TIR,
    float* __restrict__ out)
{
    __shared__ float vbuf[2][NN];
    __shared__ float part[3][256];

    int bid = blockIdx.x;                 // [0, 2*NB*NH)
    int tensor = bid / (NB * NH);
    int rem = bid - tensor * (NB * NH);
    int b = rem / NH;
    int h = rem - b * NH;

    const float* A = tensor ? TIR : RGB;
    const size_t bh_off = (size_t)(b * NH + h) * MAT;
    const size_t l_stride = (size_t)NB * NH * MAT;

    int tid = threadIdx.x;
    int j = tid & 255;        // output column
    int q = tid >> 8;         // k-quarter (0..3)

    // quarters 0..2 are exactly 48 = 3*16; quarter 3 is 53 = 3*16 + 5
    const int kq[5] = {0, 48, 96, 144, 197};

    if (tid < NN) vbuf[0][tid] = A[bh_off + 11 * l_stride + tid];
    __syncthreads();

    int cur = 0;
    for (int l = 10; l >= 0; --l) {
        const float* M = A + bh_off + (size_t)l * l_stride;
        float acc = 0.f;
        if (j < NN) {
            const float* col = M + j;
            const float* v = vbuf[cur];
            int k = kq[q];
            const int k1 = kq[q + 1];
            for (; k + 16 <= k1; k += 16) {
                float x[16];
                #pragma unroll
                for (int u = 0; u < 16; ++u)
                    x[u] = col[(size_t)(k + u) * NN];   // 16 loads in flight
                #pragma unroll
                for (int u = 0; u < 16; ++u)
                    acc = fmaf(v[k + u], x[u], acc);
            }
            for (; k < k1; ++k)
                acc = fmaf(v[k], col[(size_t)k * NN], acc);
        }
        if (q) part[q - 1][j] = acc;
        __syncthreads();
        if (!q && j < NN)
            vbuf[cur ^ 1][j] = acc + part[0][j] + part[1][j] + part[2][j];
        __syncthreads();
        cur ^= 1;
    }

    // top-KSEL of scores = vbuf[cur][1..196] via rank counting.
    // Strict '>' reproduces top_k's set for distinct values; a borderline
    // fp flip only matters if NONE of the other 23 (tensor,h) selections
    // pick that element (P ~ 2^-23).
    const float* vf = vbuf[cur];
    if (tid < NN - 1) {
        float my = vf[1 + tid];
        int rank = 0;
        for (int k = 0; k < NN - 1; ++k)
            rank += (vf[1 + k] > my) ? 1 : 0;
        if (rank < KSEL) {
            out[2 * (b * NN + tid) + 0] = 0.f;
            out[2 * (b * NN + tid) + 1] = 1.f;
        }
    }
}

extern "C" void kernel_launch(void* const* d_in, const int* in_sizes, int n_in,
                              void* d_out, int out_size, void* d_ws, size_t ws_size,
                              hipStream_t stream) {
    const float* RGB = (const float*)d_in[0];
    const float* TIR = (const float*)d_in[1];
    float* out = (float*)d_out;

    int total = NB * NN;
    init_out_kernel<<<(total + 255) / 256, 256, 0, stream>>>(out);

    chain_topk_kernel<<<2 * NB * NH, 1024, 0, stream>>>(RGB, TIR, out);
}